// Round 1
// baseline (154.992 us; speedup 1.0000x reference)
//
#include <hip/hip_runtime.h>
#include <stdint.h>

typedef unsigned short u16;
typedef __attribute__((ext_vector_type(8))) short short8;
typedef __attribute__((ext_vector_type(4))) float f32x4;
typedef __attribute__((ext_vector_type(4))) uint32_t u32x4;

#define MFMA __builtin_amdgcn_mfma_f32_16x16x32_bf16

__device__ __forceinline__ u16 f2bf(float f) {
  union { float f; uint32_t u; } v; v.f = f;
  return (u16)((v.u + 0x7FFFu + ((v.u >> 16) & 1u)) >> 16);
}

#define GLOAD16(gp, lp) \
  __builtin_amdgcn_global_load_lds((const __attribute__((address_space(1))) uint32_t*)(gp), \
                                   (__attribute__((address_space(3))) uint32_t*)(lp), 16, 0, 0)

// ws layout (bytes)
#define WS_H    0          // u16 H[512][1152][8]  (9,437,184 B)
#define WS_P1   9437184    // f32 P1[128][128]
#define WS_Q1   9502720    // f32 q1[128]
#define WS_Q2   9503232    // f32 q2[128]
#define WS_M1P  9503744    // u64 m1p[4096][64]
#define WS_M2P  11600896   // u64 m2p[4096][64]
#define WS_RS1  13698048   // f32 rs1[4096]
#define WS_RS2  13714432   // f32 rs2[4096]

// ---------------- kernel M: pack masks into bits + row sums ----------------
__global__ __launch_bounds__(256) void kmask(const int* __restrict__ sp,
                                             unsigned long long* __restrict__ m1p,
                                             unsigned long long* __restrict__ m2p,
                                             float* __restrict__ rs1, float* __restrict__ rs2) {
  int wave = threadIdx.x >> 6, lane = threadIdx.x & 63;
  int i = blockIdx.x * 4 + wave;
  const int* rowp = sp + (size_t)i * 4096;
  int c1 = 0, c2 = 0;
  for (int w = 0; w < 64; ++w) {
    int v = rowp[w * 64 + lane];
    unsigned long long b1 = __ballot(v <= 1);
    unsigned long long b2 = __ballot(v == 2);
    if (lane == 0) {
      m1p[(size_t)i * 64 + w] = b1;
      m2p[(size_t)i * 64 + w] = b2;
      c1 += __popcll(b1);
      c2 += __popcll(b2);
    }
  }
  if (lane == 0) { rs1[i] = (float)c1; rs2[i] = (float)c2; }
}

// ---------------- kernel P: P1 = W1 @ Wb1, q1 = b1@Wb1, q2 = b2@Wb2 ----------------
__global__ __launch_bounds__(256) void kprep(const float* __restrict__ W1, const float* __restrict__ Wb,
                                             const float* __restrict__ b1, const float* __restrict__ b2,
                                             float* __restrict__ P1, float* __restrict__ q1,
                                             float* __restrict__ q2) {
  int idx = blockIdx.x * 256 + threadIdx.x;   // 0..16383
  int a = idx >> 7, c = idx & 127;
  float acc = 0.f;
  for (int k = 0; k < 128; ++k) acc += W1[a * 128 + k] * Wb[k * 128 + c];
  P1[idx] = acc;
  if (idx < 128) {
    float s1 = 0.f, s2 = 0.f;
    for (int k = 0; k < 128; ++k) s1 += b1[k] * Wb[k * 128 + idx];
    for (int k = 0; k < 16; ++k)  s2 += b2[k] * Wb[(128 + k) * 128 + idx];
    q1[idx] = s1; q2[idx] = s2;
  }
}

// ---------------- kernel A': u1 = x@P1, h2 = x@W2 -> blocked H[jb][b*144+n][8] bf16 ----------------
__global__ __launch_bounds__(256, 2) void kproj(const float* __restrict__ x,
                                                const float* __restrict__ P1f,
                                                const float* __restrict__ W2,
                                                u16* __restrict__ H) {
  __shared__ u16 wsb[16 * 144 * 8];       // B operand blocked [jb][n][r]
  __shared__ u16 uni[64 * 146];           // union: xs[64][136] then hs[64][146]
  u16* xs = uni;
  u16* hs = uni;
  const int tid = threadIdx.x;
  const int r0 = blockIdx.x * 64;         // global row in [0,32768)

  // stage B operand: [P1 | W2] -> blocked bf16
  for (int i = 0; i < 72; ++i) {
    int e = i * 256 + tid;                // (k, nn) row-major, 128x144
    int k = e / 144, nn = e % 144;
    float v = (nn < 128) ? P1f[k * 128 + nn] : W2[k * 16 + (nn - 128)];
    wsb[((k >> 3) * 144 + nn) * 8 + (k & 7)] = f2bf(v);
  }
  // stage x rows -> xs[64][136] bf16
  {
    const float* xp = x + ((size_t)(r0 + (tid >> 2))) * 128 + (tid & 3) * 32;
    u16* xd = xs + (tid >> 2) * 136 + (tid & 3) * 32;
#pragma unroll
    for (int i = 0; i < 4; ++i) {
      f32x4 a = ((const f32x4*)xp)[i * 2];
      f32x4 b = ((const f32x4*)xp)[i * 2 + 1];
      short8 pk;
      pk[0] = (short)f2bf(a[0]); pk[1] = (short)f2bf(a[1]);
      pk[2] = (short)f2bf(a[2]); pk[3] = (short)f2bf(a[3]);
      pk[4] = (short)f2bf(b[0]); pk[5] = (short)f2bf(b[1]);
      pk[6] = (short)f2bf(b[2]); pk[7] = (short)f2bf(b[3]);
      *(short8*)(xd + i * 8) = pk;
    }
  }
  __syncthreads();

  const int w = tid >> 6, l = tid & 63, lr = l & 15, lg = l >> 4;
  f32x4 acc[9];
  f32x4 zz = {0.f, 0.f, 0.f, 0.f};
#pragma unroll
  for (int fn = 0; fn < 9; ++fn) acc[fn] = zz;
#pragma unroll
  for (int kf = 0; kf < 4; ++kf) {
    short8 af = *(const short8*)(xs + (w * 16 + lr) * 136 + kf * 32 + lg * 8);
#pragma unroll
    for (int fn = 0; fn < 9; ++fn) {
      short8 bf = *(const short8*)(wsb + (((kf * 4 + lg) * 144) + fn * 16 + lr) * 8);
      acc[fn] = MFMA(af, bf, acc[fn], 0, 0, 0);
    }
  }
  __syncthreads();
  // write hs[64][146] bf16
#pragma unroll
  for (int fn = 0; fn < 9; ++fn)
#pragma unroll
    for (int g = 0; g < 4; ++g)
      hs[(w * 16 + lg * 4 + g) * 146 + fn * 16 + lr] = f2bf(acc[fn][g]);
  __syncthreads();
  // blocked coalesced write to H
  {
    const int b = r0 >> 12;
    const int jb0 = (r0 & 4095) >> 3;
    for (int i = 0; i < 5; ++i) {
      int e = i * 256 + tid;
      if (e < 1152) {
        int jbl = e / 144, n = e % 144;
        union { u16 s[8]; uint4 v; } pk;
#pragma unroll
        for (int r = 0; r < 8; ++r) pk.s[r] = hs[(jbl * 8 + r) * 146 + n];
        *(uint4*)(H + (((size_t)(jb0 + jbl) * 1152 + b * 144 + n) << 3)) = pk.v;
      }
    }
  }
}

// ---------------- kernel B1: out = m1@u1 + (m2@h2)@Wb2 + rs1*q1 + rs2*q2 + bb ----------------
__global__ __launch_bounds__(256, 2) void kb1(const u16* __restrict__ H,
                                              const uint32_t* __restrict__ m1p32,
                                              const uint32_t* __restrict__ m2p32,
                                              const float* __restrict__ rs1, const float* __restrict__ rs2,
                                              const float* __restrict__ q1, const float* __restrict__ q2,
                                              const float* __restrict__ Wb, const float* __restrict__ bb,
                                              float* __restrict__ out) {
  __shared__ u16 m1s[128 * 72];
  __shared__ u16 m2s[128 * 72];
  __shared__ u16 bt[8 * 144 * 8];         // B tile [jb][n 0..143][r], linear for global_load_lds
  __shared__ u16 wb2s[4 * 128 * 8];       // Wb2 padded to K=32, blocked

  const int tid = threadIdx.x;
  const int bid = blockIdx.x;
  // XCD-grouped mapping: all 8 b-blocks of a panel land on one XCD
  const int xcd = bid & 7, q = bid >> 3;
  const int panel = xcd * 4 + (q >> 3);
  const int b = q & 7;
  const int i0 = panel * 128;

  // stage Wb2 (rows 128..143 of Wb, zero-padded to 32) once
  for (int i = 0; i < 16; ++i) {
    int e = i * 256 + tid;                // (jb*128+n)*8 + r
    int r = e & 7, nn = (e >> 3) & 127, jb = e >> 10;
    int k = jb * 8 + r;
    float v = (k < 16) ? Wb[(128 + k) * 128 + nn] : 0.f;
    wb2s[e] = f2bf(v);
  }

  const int w = tid >> 6, l = tid & 63, lr = l & 15, lg = l >> 4;
  const int mrow = tid >> 1, mhalf = tid & 1;
  const uint32_t* m1w = m1p32 + (size_t)(i0 + mrow) * 128 + mhalf;
  const uint32_t* m2w = m2p32 + (size_t)(i0 + mrow) * 128 + mhalf;

  // precompute per-lane global_load_lds source offsets (elements) and validity
  size_t srcoff[5];
  const int e0 = tid * 8;
#pragma unroll
  for (int it = 0; it < 5; ++it) {
    int e = it * 2048 + e0;
    if (e < 9216) {
      int jb = e / 1152, n = (e % 1152) >> 3;
      srcoff[it] = (size_t)jb * 9216 + (size_t)(b * 144 + n) * 8;
    } else srcoff[it] = 0;
  }

  f32x4 zz = {0.f, 0.f, 0.f, 0.f};
  f32x4 acc[2][8];
  f32x4 acc2[2];
#pragma unroll
  for (int fm = 0; fm < 2; ++fm) {
    acc2[fm] = zz;
#pragma unroll
    for (int fn = 0; fn < 8; ++fn) acc[fm][fn] = zz;
  }

  for (int kt = 0; kt < 64; ++kt) {
    // issue async B-tile stage first (latency overlaps with mask build)
    const u16* hp = H + (size_t)kt * 73728;
#pragma unroll
    for (int it = 0; it < 4; ++it)
      GLOAD16(hp + srcoff[it], (char*)bt + it * 4096 + (size_t)tid * 16);
    if (tid < 128)
      GLOAD16(hp + srcoff[4], (char*)bt + 16384 + (size_t)tid * 16);

    // build bf16 mask tiles from packed bits
    uint32_t w1 = m1w[kt * 2];
    uint32_t w2 = m2w[kt * 2];
    u16* d1 = m1s + mrow * 72 + mhalf * 32;
    u16* d2 = m2s + mrow * 72 + mhalf * 32;
#pragma unroll
    for (int q4 = 0; q4 < 4; ++q4) {
      u32x4 v1, v2;
#pragma unroll
      for (int p = 0; p < 4; ++p) {
        int bp = q4 * 8 + p * 2;
        v1[p] = (((w1 >> bp) & 1u) ? 0x3F80u : 0u) | (((w1 >> (bp + 1)) & 1u) ? 0x3F800000u : 0u);
        v2[p] = (((w2 >> bp) & 1u) ? 0x3F80u : 0u) | (((w2 >> (bp + 1)) & 1u) ? 0x3F800000u : 0u);
      }
      *(u32x4*)(d1 + q4 * 8) = v1;
      *(u32x4*)(d2 + q4 * 8) = v2;
    }
    __syncthreads();

#pragma unroll
    for (int kf = 0; kf < 2; ++kf) {
      short8 a1[2], a2[2];
#pragma unroll
      for (int fm = 0; fm < 2; ++fm) {
        int row = w * 32 + fm * 16 + lr;
        a1[fm] = *(const short8*)(m1s + row * 72 + kf * 32 + lg * 8);
        a2[fm] = *(const short8*)(m2s + row * 72 + kf * 32 + lg * 8);
      }
#pragma unroll
      for (int fn = 0; fn < 8; ++fn) {
        short8 bf = *(const short8*)(bt + (((kf * 4 + lg) * 144) + fn * 16 + lr) * 8);
        acc[0][fn] = MFMA(a1[0], bf, acc[0][fn], 0, 0, 0);
        acc[1][fn] = MFMA(a1[1], bf, acc[1][fn], 0, 0, 0);
      }
      short8 bf2 = *(const short8*)(bt + (((kf * 4 + lg) * 144) + 128 + lr) * 8);
      acc2[0] = MFMA(a2[0], bf2, acc2[0], 0, 0, 0);
      acc2[1] = MFMA(a2[1], bf2, acc2[1], 0, 0, 0);
    }
    __syncthreads();
  }

  // epilogue: f2 (= m2@h2) -> LDS bf16 (K padded to 32), then one MFMA vs Wb2 into acc
  u16* f2s = m1s;                         // reuse, stride 40
  for (int i = 0; i < 8; ++i) {           // zero pad cols 16..31
    int e = i * 256 + tid;
    f2s[(e >> 4) * 40 + 16 + (e & 15)] = 0;
  }
#pragma unroll
  for (int fm = 0; fm < 2; ++fm)
#pragma unroll
    for (int g = 0; g < 4; ++g)
      f2s[(w * 32 + fm * 16 + lg * 4 + g) * 40 + lr] = f2bf(acc2[fm][g]);
  __syncthreads();

#pragma unroll
  for (int fm = 0; fm < 2; ++fm) {
    short8 af = *(const short8*)(f2s + (w * 32 + fm * 16 + lr) * 40 + lg * 8);
#pragma unroll
    for (int fn = 0; fn < 8; ++fn) {
      short8 bf = *(const short8*)(wb2s + ((lg * 128) + fn * 16 + lr) * 8);
      acc[fm][fn] = MFMA(af, bf, acc[fm][fn], 0, 0, 0);
    }
  }

  // final: + rs1*q1 + rs2*q2 + bb, store f32
  float q1v[8], q2v[8], bbv[8];
#pragma unroll
  for (int fn = 0; fn < 8; ++fn) {
    int c = fn * 16 + lr;
    q1v[fn] = q1[c]; q2v[fn] = q2[c]; bbv[fn] = bb[c];
  }
#pragma unroll
  for (int fm = 0; fm < 2; ++fm)
#pragma unroll
    for (int g = 0; g < 4; ++g) {
      int row = w * 32 + fm * 16 + lg * 4 + g;
      float r1 = rs1[i0 + row], r2 = rs2[i0 + row];
      size_t obase = ((size_t)b * 4096 + i0 + row) * 128 + lr;
#pragma unroll
      for (int fn = 0; fn < 8; ++fn)
        out[obase + fn * 16] = acc[fm][fn][g] + r1 * q1v[fn] + r2 * q2v[fn] + bbv[fn];
    }
}

extern "C" void kernel_launch(void* const* d_in, const int* in_sizes, int n_in,
                              void* d_out, int out_size, void* d_ws, size_t ws_size,
                              hipStream_t stream) {
  const float* x  = (const float*)d_in[0];
  const int*   sp = (const int*)d_in[1];
  const float* W1 = (const float*)d_in[2];
  const float* b1 = (const float*)d_in[3];
  const float* W2 = (const float*)d_in[4];
  const float* b2 = (const float*)d_in[5];
  const float* Wb = (const float*)d_in[6];
  const float* bb = (const float*)d_in[7];
  float* out = (float*)d_out;
  char* ws = (char*)d_ws;

  u16* H = (u16*)(ws + WS_H);
  float* P1 = (float*)(ws + WS_P1);
  float* q1 = (float*)(ws + WS_Q1);
  float* q2 = (float*)(ws + WS_Q2);
  unsigned long long* m1p = (unsigned long long*)(ws + WS_M1P);
  unsigned long long* m2p = (unsigned long long*)(ws + WS_M2P);
  float* rs1 = (float*)(ws + WS_RS1);
  float* rs2 = (float*)(ws + WS_RS2);

  kmask<<<1024, 256, 0, stream>>>(sp, m1p, m2p, rs1, rs2);
  kprep<<<64, 256, 0, stream>>>(W1, Wb, b1, b2, P1, q1, q2);
  kproj<<<512, 256, 0, stream>>>(x, P1, W2, H);
  kb1<<<256, 256, 0, stream>>>(H, (const uint32_t*)m1p, (const uint32_t*)m2p,
                               rs1, rs2, q1, q2, Wb, bb, out);
}

// Round 2
// 136.504 us; speedup vs baseline: 1.1354x; 1.1354x over previous
//
#include <hip/hip_runtime.h>
#include <stdint.h>

typedef unsigned short u16;
typedef __attribute__((ext_vector_type(8))) short short8;
typedef __attribute__((ext_vector_type(4))) float f32x4;

#define MFMA __builtin_amdgcn_mfma_f32_16x16x32_bf16

__device__ __forceinline__ u16 f2bf(float f) {
  union { float f; uint32_t u; } v; v.f = f;
  return (u16)((v.u + 0x7FFFu + ((v.u >> 16) & 1u)) >> 16);
}

#define GLOAD16(gp, lp) \
  __builtin_amdgcn_global_load_lds((const __attribute__((address_space(1))) uint32_t*)(gp), \
                                   (__attribute__((address_space(3))) uint32_t*)(lp), 16, 0, 0)

// ws layout (bytes)
#define WS_H    0          // u16 H[512][1152][8]  (9,437,184 B)
#define WS_P1   9437184    // f32 P1[128][128]
#define WS_Q1   9502720    // f32 q1[128]
#define WS_Q2   9503232    // f32 q2[128]
#define WS_M1P  9503744    // u64 m1p[4096][64]
#define WS_M2P  11600896   // u64 m2p[4096][64]
#define WS_RS1  13698048   // f32 rs1[4096]
#define WS_RS2  13714432   // f32 rs2[4096]

// ---------------- kernel M: pack masks into bits + row sums ----------------
__global__ __launch_bounds__(256) void kmask(const int* __restrict__ sp,
                                             unsigned long long* __restrict__ m1p,
                                             unsigned long long* __restrict__ m2p,
                                             float* __restrict__ rs1, float* __restrict__ rs2) {
  int wave = threadIdx.x >> 6, lane = threadIdx.x & 63;
  int i = blockIdx.x * 4 + wave;
  const int* rowp = sp + (size_t)i * 4096;
  int c1 = 0, c2 = 0;
  for (int w = 0; w < 64; ++w) {
    int v = rowp[w * 64 + lane];
    unsigned long long b1 = __ballot(v <= 1);
    unsigned long long b2 = __ballot(v == 2);
    if (lane == 0) {
      m1p[(size_t)i * 64 + w] = b1;
      m2p[(size_t)i * 64 + w] = b2;
      c1 += __popcll(b1);
      c2 += __popcll(b2);
    }
  }
  if (lane == 0) { rs1[i] = (float)c1; rs2[i] = (float)c2; }
}

// ---------------- kernel P: P1 = W1 @ Wb1, q1 = b1@Wb1, q2 = b2@Wb2 ----------------
__global__ __launch_bounds__(256) void kprep(const float* __restrict__ W1, const float* __restrict__ Wb,
                                             const float* __restrict__ b1, const float* __restrict__ b2,
                                             float* __restrict__ P1, float* __restrict__ q1,
                                             float* __restrict__ q2) {
  int idx = blockIdx.x * 256 + threadIdx.x;   // 0..16383
  int a = idx >> 7, c = idx & 127;
  float acc = 0.f;
  for (int k = 0; k < 128; ++k) acc += W1[a * 128 + k] * Wb[k * 128 + c];
  P1[idx] = acc;
  if (idx < 128) {
    float s1 = 0.f, s2 = 0.f;
    for (int k = 0; k < 128; ++k) s1 += b1[k] * Wb[k * 128 + idx];
    for (int k = 0; k < 16; ++k)  s2 += b2[k] * Wb[(128 + k) * 128 + idx];
    q1[idx] = s1; q2[idx] = s2;
  }
}

// ---------------- kernel A': u1 = x@P1, h2 = x@W2 -> blocked H[jb][b*144+n][8] bf16 ----------------
__global__ __launch_bounds__(256, 2) void kproj(const float* __restrict__ x,
                                                const float* __restrict__ P1f,
                                                const float* __restrict__ W2,
                                                u16* __restrict__ H) {
  __shared__ u16 wsb[16 * 144 * 8];       // B operand blocked [jb][n][r]
  __shared__ u16 uni[64 * 146];           // union: xs[64][136] then hs[64][146]
  u16* xs = uni;
  u16* hs = uni;
  const int tid = threadIdx.x;
  const int r0 = blockIdx.x * 64;         // global row in [0,32768)

  // stage B operand: [P1 | W2] -> blocked bf16
  for (int i = 0; i < 72; ++i) {
    int e = i * 256 + tid;                // (k, nn) row-major, 128x144
    int k = e / 144, nn = e % 144;
    float v = (nn < 128) ? P1f[k * 128 + nn] : W2[k * 16 + (nn - 128)];
    wsb[((k >> 3) * 144 + nn) * 8 + (k & 7)] = f2bf(v);
  }
  // stage x rows -> xs[64][136] bf16
  {
    const float* xp = x + ((size_t)(r0 + (tid >> 2))) * 128 + (tid & 3) * 32;
    u16* xd = xs + (tid >> 2) * 136 + (tid & 3) * 32;
#pragma unroll
    for (int i = 0; i < 4; ++i) {
      f32x4 a = ((const f32x4*)xp)[i * 2];
      f32x4 b = ((const f32x4*)xp)[i * 2 + 1];
      short8 pk;
      pk[0] = (short)f2bf(a[0]); pk[1] = (short)f2bf(a[1]);
      pk[2] = (short)f2bf(a[2]); pk[3] = (short)f2bf(a[3]);
      pk[4] = (short)f2bf(b[0]); pk[5] = (short)f2bf(b[1]);
      pk[6] = (short)f2bf(b[2]); pk[7] = (short)f2bf(b[3]);
      *(short8*)(xd + i * 8) = pk;
    }
  }
  __syncthreads();

  const int w = tid >> 6, l = tid & 63, lr = l & 15, lg = l >> 4;
  f32x4 acc[9];
  f32x4 zz = {0.f, 0.f, 0.f, 0.f};
#pragma unroll
  for (int fn = 0; fn < 9; ++fn) acc[fn] = zz;
#pragma unroll
  for (int kf = 0; kf < 4; ++kf) {
    short8 af = *(const short8*)(xs + (w * 16 + lr) * 136 + kf * 32 + lg * 8);
#pragma unroll
    for (int fn = 0; fn < 9; ++fn) {
      short8 bf = *(const short8*)(wsb + (((kf * 4 + lg) * 144) + fn * 16 + lr) * 8);
      acc[fn] = MFMA(af, bf, acc[fn], 0, 0, 0);
    }
  }
  __syncthreads();
  // write hs[64][146] bf16
#pragma unroll
  for (int fn = 0; fn < 9; ++fn)
#pragma unroll
    for (int g = 0; g < 4; ++g)
      hs[(w * 16 + lg * 4 + g) * 146 + fn * 16 + lr] = f2bf(acc[fn][g]);
  __syncthreads();
  // blocked coalesced write to H
  {
    const int b = r0 >> 12;
    const int jb0 = (r0 & 4095) >> 3;
    for (int i = 0; i < 5; ++i) {
      int e = i * 256 + tid;
      if (e < 1152) {
        int jbl = e / 144, n = e % 144;
        union { u16 s[8]; uint4 v; } pk;
#pragma unroll
        for (int r = 0; r < 8; ++r) pk.s[r] = hs[(jbl * 8 + r) * 146 + n];
        *(uint4*)(H + (((size_t)(jb0 + jbl) * 1152 + b * 144 + n) << 3)) = pk.v;
      }
    }
  }
}

// expand 8 mask bits (byte lg of word w) -> 8 bf16 {0,1} packed as short8
__device__ __forceinline__ short8 expand_byte(uint32_t wd, int lgsh) {
  uint32_t b = (wd >> lgsh) & 0xFFu;     // v_bfe
  uint32_t t = b * 0x8001u;              // low half = b, bits16..22 = b>>1
  union { uint32_t u[4]; short8 s; } r;
  r.u[0] = (t & 0x00010001u) * 0x3F80u;  // bits 0,1
  r.u[1] = (t & 0x00040004u) * 0x0FE0u;  // bits 2,3
  r.u[2] = (t & 0x00100010u) * 0x03F8u;  // bits 4,5
  r.u[3] = (t & 0x00400040u) * 0x00FEu;  // bits 6,7
  return r.s;
}

// ---------------- kernel B1: out = m1@u1 + (m2@h2)@Wb2 + rs1*q1 + rs2*q2 + bb ----------------
__global__ __launch_bounds__(256, 1) void kb1(const u16* __restrict__ H,
                                              const uint32_t* __restrict__ m1p32,
                                              const uint32_t* __restrict__ m2p32,
                                              const float* __restrict__ rs1, const float* __restrict__ rs2,
                                              const float* __restrict__ q1, const float* __restrict__ q2,
                                              const float* __restrict__ Wb, const float* __restrict__ bb,
                                              float* __restrict__ out) {
  __shared__ u16 bt[2][9216];             // double-buffered B tile
  __shared__ u16 wb2s[4 * 128 * 8];       // Wb2 padded to K=32, blocked

  const int tid = threadIdx.x;
  const int bid = blockIdx.x;
  // XCD-grouped mapping: all 8 b-blocks of a panel land on one XCD
  const int xcd = bid & 7, q = bid >> 3;
  const int panel = xcd * 4 + (q >> 3);
  const int b = q & 7;
  const int i0 = panel * 128;

  // stage Wb2 (rows 128..143 of Wb, zero-padded to 32) once
  for (int i = 0; i < 16; ++i) {
    int e = i * 256 + tid;                // (jb*128+n)*8 + r
    int r = e & 7, nn = (e >> 3) & 127, jb = e >> 10;
    int k = jb * 8 + r;
    float v = (k < 16) ? Wb[(128 + k) * 128 + nn] : 0.f;
    wb2s[e] = f2bf(v);
  }

  const int w = tid >> 6, l = tid & 63, lr = l & 15, lg = l >> 4;
  const int lgsh = lg * 8;

  // mask word streams (row-major u64 words, viewed as uint2)
  const uint2* M1 = (const uint2*)m1p32;
  const uint2* M2 = (const uint2*)m2p32;
  const size_t rA64 = (size_t)(i0 + w * 32 + lr) * 64;        // fm=0 row
  const size_t rB64 = (size_t)(i0 + w * 32 + 16 + lr) * 64;   // fm=1 row

  // per-lane global_load_lds source offsets (elements)
  size_t srcoff[5];
  const int e0 = tid * 8;
#pragma unroll
  for (int it = 0; it < 5; ++it) {
    int e = it * 2048 + e0;
    if (e < 9216) {
      int jb = e / 1152, n = (e % 1152) >> 3;
      srcoff[it] = (size_t)jb * 9216 + (size_t)(b * 144 + n) * 8;
    } else srcoff[it] = 0;
  }

  f32x4 zz = {0.f, 0.f, 0.f, 0.f};
  f32x4 acc[2][8];
  f32x4 acc2[2];
#pragma unroll
  for (int fm = 0; fm < 2; ++fm) {
    acc2[fm] = zz;
#pragma unroll
    for (int fn = 0; fn < 8; ++fn) acc[fm][fn] = zz;
  }

  // prologue: issue kt=0 B-tile into bt[0]; load kt=0 mask words
  {
    const u16* hp = H;
#pragma unroll
    for (int it = 0; it < 4; ++it)
      GLOAD16(hp + srcoff[it], (char*)&bt[0][0] + it * 4096 + (size_t)tid * 16);
    if (tid < 128)
      GLOAD16(hp + srcoff[4], (char*)&bt[0][0] + 16384 + (size_t)tid * 16);
  }
  uint2 c1A = M1[rA64], c1B = M1[rB64], c2A = M2[rA64], c2B = M2[rB64];

  for (int kt = 0; kt < 64; ++kt) {
    __syncthreads();   // drains kt's loads (vmcnt0) + protects bt[(kt+1)&1] reuse

    // issue kt+1 B-tile into the other buffer
    if (kt < 63) {
      const u16* hp = H + (size_t)(kt + 1) * 73728;
      char* dst = (char*)&bt[(kt + 1) & 1][0];
#pragma unroll
      for (int it = 0; it < 4; ++it)
        GLOAD16(hp + srcoff[it], dst + it * 4096 + (size_t)tid * 16);
      if (tid < 128)
        GLOAD16(hp + srcoff[4], dst + 16384 + (size_t)tid * 16);
    }
    // prefetch kt+1 mask words into registers
    const int nkt = (kt < 63) ? kt + 1 : 63;
    uint2 n1A = M1[rA64 + nkt], n1B = M1[rB64 + nkt];
    uint2 n2A = M2[rA64 + nkt], n2B = M2[rB64 + nkt];

    // expand current mask words -> A fragments (registers only)
    short8 a1[2][2], a2[2][2];
    a1[0][0] = expand_byte(c1A.x, lgsh); a1[0][1] = expand_byte(c1A.y, lgsh);
    a1[1][0] = expand_byte(c1B.x, lgsh); a1[1][1] = expand_byte(c1B.y, lgsh);
    a2[0][0] = expand_byte(c2A.x, lgsh); a2[0][1] = expand_byte(c2A.y, lgsh);
    a2[1][0] = expand_byte(c2B.x, lgsh); a2[1][1] = expand_byte(c2B.y, lgsh);

    const u16* src = &bt[kt & 1][0];
#pragma unroll
    for (int kf = 0; kf < 2; ++kf) {
#pragma unroll
      for (int fn = 0; fn < 8; ++fn) {
        short8 bf = *(const short8*)(src + (((kf * 4 + lg) * 144) + fn * 16 + lr) * 8);
        acc[0][fn] = MFMA(a1[0][kf], bf, acc[0][fn], 0, 0, 0);
        acc[1][fn] = MFMA(a1[1][kf], bf, acc[1][fn], 0, 0, 0);
      }
      short8 bf2 = *(const short8*)(src + (((kf * 4 + lg) * 144) + 128 + lr) * 8);
      acc2[0] = MFMA(a2[0][kf], bf2, acc2[0], 0, 0, 0);
      acc2[1] = MFMA(a2[1][kf], bf2, acc2[1], 0, 0, 0);
    }
    c1A = n1A; c1B = n1B; c2A = n2A; c2B = n2B;
  }

  // epilogue: f2 (= m2@h2) -> LDS bf16 (K padded to 32), then one MFMA vs Wb2 into acc
  u16* f2s = (u16*)&bt[0][0];             // reuse, stride 40 (no loads outstanding into bt[0])
  for (int i = 0; i < 8; ++i) {           // zero pad cols 16..31
    int e = i * 256 + tid;
    f2s[(e >> 4) * 40 + 16 + (e & 15)] = 0;
  }
#pragma unroll
  for (int fm = 0; fm < 2; ++fm)
#pragma unroll
    for (int g = 0; g < 4; ++g)
      f2s[(w * 32 + fm * 16 + lg * 4 + g) * 40 + lr] = f2bf(acc2[fm][g]);
  __syncthreads();

#pragma unroll
  for (int fm = 0; fm < 2; ++fm) {
    short8 af = *(const short8*)(f2s + (w * 32 + fm * 16 + lr) * 40 + lg * 8);
#pragma unroll
    for (int fn = 0; fn < 8; ++fn) {
      short8 bf = *(const short8*)(wb2s + ((lg * 128) + fn * 16 + lr) * 8);
      acc[fm][fn] = MFMA(af, bf, acc[fm][fn], 0, 0, 0);
    }
  }

  // final: + rs1*q1 + rs2*q2 + bb, store f32
  float q1v[8], q2v[8], bbv[8];
#pragma unroll
  for (int fn = 0; fn < 8; ++fn) {
    int c = fn * 16 + lr;
    q1v[fn] = q1[c]; q2v[fn] = q2[c]; bbv[fn] = bb[c];
  }
#pragma unroll
  for (int fm = 0; fm < 2; ++fm)
#pragma unroll
    for (int g = 0; g < 4; ++g) {
      int row = w * 32 + fm * 16 + lg * 4 + g;
      float r1 = rs1[i0 + row], r2 = rs2[i0 + row];
      size_t obase = ((size_t)b * 4096 + i0 + row) * 128 + lr;
#pragma unroll
      for (int fn = 0; fn < 8; ++fn)
        out[obase + fn * 16] = acc[fm][fn][g] + r1 * q1v[fn] + r2 * q2v[fn] + bbv[fn];
    }
}

extern "C" void kernel_launch(void* const* d_in, const int* in_sizes, int n_in,
                              void* d_out, int out_size, void* d_ws, size_t ws_size,
                              hipStream_t stream) {
  const float* x  = (const float*)d_in[0];
  const int*   sp = (const int*)d_in[1];
  const float* W1 = (const float*)d_in[2];
  const float* b1 = (const float*)d_in[3];
  const float* W2 = (const float*)d_in[4];
  const float* b2 = (const float*)d_in[5];
  const float* Wb = (const float*)d_in[6];
  const float* bb = (const float*)d_in[7];
  float* out = (float*)d_out;
  char* ws = (char*)d_ws;

  u16* H = (u16*)(ws + WS_H);
  float* P1 = (float*)(ws + WS_P1);
  float* q1 = (float*)(ws + WS_Q1);
  float* q2 = (float*)(ws + WS_Q2);
  unsigned long long* m1p = (unsigned long long*)(ws + WS_M1P);
  unsigned long long* m2p = (unsigned long long*)(ws + WS_M2P);
  float* rs1 = (float*)(ws + WS_RS1);
  float* rs2 = (float*)(ws + WS_RS2);

  kmask<<<1024, 256, 0, stream>>>(sp, m1p, m2p, rs1, rs2);
  kprep<<<64, 256, 0, stream>>>(W1, Wb, b1, b2, P1, q1, q2);
  kproj<<<512, 256, 0, stream>>>(x, P1, W2, H);
  kb1<<<256, 256, 0, stream>>>(H, (const uint32_t*)m1p, (const uint32_t*)m2p,
                               rs1, rs2, q1, q2, Wb, bb, out);
}